// Round 1
// 237.482 us; speedup vs baseline: 1.0040x; 1.0040x over previous
//
#include <hip/hip_runtime.h>
#include <math.h>

// RX gate on qubit 5 of 12, batch 4096 states of dim 4096.
// out_re[i] = c*sr[i] + s*si[i^64];  out_im[i] = c*si[i] - s*sr[i^64]
// (M = c*I - i*s*X_hyd is symmetric; X_hyd is the bit-6 flip permutation.)
//
// v2: shuffle-free butterfly. In float4-index space the partner is V^16.
// Instead of exchanging via __shfl_xor (which forces a full vmcnt(0)+lgkmcnt
// drain per wave before any store), each thread OWNS the pair (i, i+16)
// [i has bit4=0], so all cross terms are thread-local registers. Each thread
// processes 2 pairs (8 independent 16B loads in flight) for load-level ILP.
// Wave-level access pattern: 256B-contiguous segments -> fully coalesced.

#define NQ_N 4096
#define NQ_BATCH 4096

typedef float f32x4 __attribute__((ext_vector_type(4)));

// total f32x4 vecs = 4096*4096/4 = 2^22 ; pairs = 2^21 ; 2 pairs/thread
#define TOTAL_PAIRS (1u << 21)
#define PAIR_OFFSET (1u << 20)   // second pair = first + half the pair space

__global__ __launch_bounds__(256)
void rx_pair_kernel(const f32x4* __restrict__ sr,
                    const f32x4* __restrict__ si,
                    const float* __restrict__ theta_p,
                    f32x4* __restrict__ out_re,
                    f32x4* __restrict__ out_im)
{
    const float half = 0.5f * theta_p[0];
    const float c = cosf(half);
    const float s = sinf(half);

    const unsigned u = blockIdx.x * blockDim.x + threadIdx.x; // pair id (lo half)

    const unsigned p0 = u;
    const unsigned p1 = u + PAIR_OFFSET;

    // pair p -> vec index i with bit4 cleared-then-spread: i = g*32 + (p&15)
    const unsigned i0 = p0 + (p0 & ~15u);
    const unsigned j0 = i0 + 16;
    const unsigned i1 = p1 + (p1 & ~15u);
    const unsigned j1 = i1 + 16;

    // 8 independent loads — all issued before any use (vmcnt pipelining)
    const f32x4 rA = sr[i0];
    const f32x4 rB = sr[j0];
    const f32x4 mA = si[i0];
    const f32x4 mB = si[j0];
    const f32x4 rC = sr[i1];
    const f32x4 rD = sr[j1];
    const f32x4 mC = si[i1];
    const f32x4 mD = si[j1];

    f32x4 reA, imA, reB, imB, reC, imC, reD, imD;
#pragma unroll
    for (int k = 0; k < 4; ++k) {
        reA[k] = fmaf(c, rA[k],  s * mB[k]);
        imA[k] = fmaf(c, mA[k], -s * rB[k]);
        reB[k] = fmaf(c, rB[k],  s * mA[k]);
        imB[k] = fmaf(c, mB[k], -s * rA[k]);
        reC[k] = fmaf(c, rC[k],  s * mD[k]);
        imC[k] = fmaf(c, mC[k], -s * rD[k]);
        reD[k] = fmaf(c, rD[k],  s * mC[k]);
        imD[k] = fmaf(c, mD[k], -s * rC[k]);
    }

    // write-once outputs: nontemporal (unchanged from v1 to isolate the
    // structural change; L3 is thrashed by harness fills either way)
    __builtin_nontemporal_store(reA, out_re + i0);
    __builtin_nontemporal_store(imA, out_im + i0);
    __builtin_nontemporal_store(reB, out_re + j0);
    __builtin_nontemporal_store(imB, out_im + j0);
    __builtin_nontemporal_store(reC, out_re + i1);
    __builtin_nontemporal_store(imC, out_im + i1);
    __builtin_nontemporal_store(reD, out_re + j1);
    __builtin_nontemporal_store(imD, out_im + j1);
}

extern "C" void kernel_launch(void* const* d_in, const int* in_sizes, int n_in,
                              void* d_out, int out_size, void* d_ws, size_t ws_size,
                              hipStream_t stream)
{
    const f32x4* sr = (const f32x4*)d_in[0];
    const f32x4* si = (const f32x4*)d_in[1];
    const float* th = (const float*)d_in[2];

    f32x4* out_re = (f32x4*)d_out;
    f32x4* out_im = out_re + ((size_t)NQ_BATCH * NQ_N / 4);

    const unsigned threads = TOTAL_PAIRS / 2;  // 2 pairs per thread -> 2^20
    const unsigned block = 256;
    const unsigned grid = threads / block;     // 4096

    rx_pair_kernel<<<grid, block, 0, stream>>>(sr, si, th, out_re, out_im);
}